// Round 7
// baseline (236.417 us; speedup 1.0000x reference)
//
#include <hip/hip_runtime.h>

// HungarianCELoss — analytic collapse of the 120-perm matching.
// targets has only 2 distinct rows (fg, bg=1-fg) => argmin over perms ==
// argmin_k (cost_fg[k]-cost_bg[k]), ties -> smallest k (lex order of perms).
// Per-element identities (x = slot logit, fg = target):
//   e = exp(-|x|); d = softplus(x)-x = log(1+e) + max(-x,0)
//   sigmoid(x) = (x>=0) ? 1/(1+e) : e/(1+e)
//   sum_k A_k = sum d (all k,n) + sum_k XF_k,  C_k = 2*XF_k - X_k
//   answer = [sum_k A_k - C_{k*}] summed over b, / (B*K*N)
//
// R7: all-k-per-block. Each block owns a contiguous 5120-px span of one
// image and processes all 5 slots, so each target element is fetched ONCE
// (logical reads 157 MB vs 262 MB in R4/R6 where 5 plane-blocks re-fetched
// target). Tests the L3/TCC serve-rate theory. unroll 1 on the pixel loop
// (R1 lesson: hoisted loads -> VGPR 136), no launch_bounds (R2 lesson:
// forced cap -> spills).

#define BB 64
#define KK 5
#define NPIX 102400     // 320*320
#define PB 20           // blocks per image
#define SPAN 5120       // NPIX / PB
#define ITERS 5         // SPAN / (256 threads * 4 floats)
#define THREADS 256
#define REC 24          // floats per block record; 22 used
#define NBLK (BB * PB)  // 1280 = 5 per CU

typedef float v4f __attribute__((ext_vector_type(4)));

__global__ void hung_pass1(const float* __restrict__ slot,   // (B,K,N)
                           const float* __restrict__ tgt,    // (B,1,N)
                           float* __restrict__ ws)           // (NBLK, REC)
{
    const int bid = blockIdx.x;
    const int b   = bid / PB;
    const int pb  = bid - b * PB;

    const float* t  = tgt  + (size_t)b * NPIX + pb * SPAN;
    const float* xb = slot + (size_t)b * KK * NPIX + pb * SPAN;

    float X[KK]  = {0,0,0,0,0};
    float XF[KK] = {0,0,0,0,0};
    float S[KK]  = {0,0,0,0,0};
    float SF[KK] = {0,0,0,0,0};
    float PX = 0.f, Tf = 0.f;

    const int tid4 = threadIdx.x * 4;
    #pragma unroll 1
    for (int i = 0; i < ITERS; ++i) {
        const int off = tid4 + i * (THREADS * 4);
        const v4f fg4 = *reinterpret_cast<const v4f*>(t + off);
        #pragma unroll
        for (int k = 0; k < KK; ++k) {
            const v4f x4 = *reinterpret_cast<const v4f*>(xb + (size_t)k * NPIX + off);
            #pragma unroll
            for (int u = 0; u < 4; ++u) {
                const float x  = x4[u];
                const float fg = fg4[u];
                const float e  = __expf(-fabsf(x));      // exp(-|x|)
                const float qq = 1.0f + e;
                const float r  = __builtin_amdgcn_rcpf(qq);
                const float d  = __logf(qq) + fmaxf(-x, 0.0f);   // softplus(x)-x
                const float s  = (x >= 0.0f) ? r : e * r;        // sigmoid(x)
                PX   += d;
                X[k] += x;
                XF[k] = fmaf(x, fg, XF[k]);
                S[k] += s;
                SF[k] = fmaf(s, fg, SF[k]);
            }
        }
        Tf += (fg4.x + fg4.y) + (fg4.z + fg4.w);
    }

    // block reduce 22 values: per-wave butterfly (wave=64) then LDS combine
    float v[22];
    #pragma unroll
    for (int k = 0; k < KK; ++k) {
        v[k]      = X[k];
        v[5 + k]  = XF[k];
        v[10 + k] = S[k];
        v[15 + k] = SF[k];
    }
    v[20] = PX;
    v[21] = Tf;
    #pragma unroll
    for (int j = 0; j < 22; ++j) {
        float x = v[j];
        #pragma unroll
        for (int off = 32; off > 0; off >>= 1) x += __shfl_down(x, off, 64);
        v[j] = x;
    }
    __shared__ float red[THREADS / 64][22];
    const int lane = threadIdx.x & 63;
    const int w    = threadIdx.x >> 6;
    if (lane == 0) {
        #pragma unroll
        for (int j = 0; j < 22; ++j) red[w][j] = v[j];
    }
    __syncthreads();
    if (threadIdx.x < 22) {
        const int j = threadIdx.x;
        ws[(size_t)bid * REC + j] =
            red[0][j] + red[1][j] + red[2][j] + red[3][j];
    }
}

__global__ __launch_bounds__(256) void hung_pass2(const float* __restrict__ ws,
                                                  float* __restrict__ out)
{
    __shared__ float red[BB][22];
    // sum the PB records of each image; work item = (b, j)
    for (int idx = threadIdx.x; idx < BB * 22; idx += 256) {
        const int b = idx / 22, j = idx - b * 22;
        float s = 0.f;
        #pragma unroll 4
        for (int pb = 0; pb < PB; ++pb)
            s += ws[(size_t)(b * PB + pb) * REC + j];
        red[b][j] = s;
    }
    __syncthreads();
    if (threadIdx.x < 64) {            // wave 0: one image per lane
        const int b = threadIdx.x;
        const float* v = red[b];
        const float Tf = v[21];
        const float Tb = (float)NPIX - Tf;
        float best = 3.402823466e+38f; int kb = 0;
        float xfsum = 0.f;
        #pragma unroll
        for (int k = 0; k < KK; ++k) {
            const float Sv = v[10 + k], Iv = v[15 + k];   // S_k, inter_fg
            const float cf = 1.f - Iv / (Sv + Tf - Iv + 1e-6f);
            const float Ib = Sv - Iv;
            const float cb = 1.f - Ib / (Sv + Tb - Ib + 1e-6f);
            const float dd = cf - cb;
            if (dd < best) { best = dd; kb = k; }  // strict < : ties -> smallest k
            xfsum += v[5 + k];
        }
        float res = v[20] + xfsum - (2.f * v[5 + kb] - v[kb]);  // - C_{k*}
        #pragma unroll
        for (int off = 32; off > 0; off >>= 1) res += __shfl_down(res, off, 64);
        if (b == 0) out[0] = res * (1.0f / 32768000.0f);   // / (B*K*N)
    }
}

extern "C" void kernel_launch(void* const* d_in, const int* in_sizes, int n_in,
                              void* d_out, int out_size, void* d_ws, size_t ws_size,
                              hipStream_t stream) {
    // setup_inputs order: fg_logits (unused by reference!), slot_logits, target
    const float* slot = (const float*)d_in[1];
    const float* tgt  = (const float*)d_in[2];
    float* out = (float*)d_out;
    float* ws  = (float*)d_ws;

    hung_pass1<<<NBLK, THREADS, 0, stream>>>(slot, tgt, ws);
    hung_pass2<<<1, 256, 0, stream>>>(ws, out);
}